// Round 10
// baseline (66.009 us; speedup 1.0000x reference)
//
#include <hip/hip_runtime.h>
#include <math.h>

#define NI   128
#define ND   32
#define NH   4
#define NNEI 120
#define KVW  640            // (ND+NI)*NH
#define NCOL 512            // NH*NI
#define ATOMS 4

// ---- DPP helpers: 16-lane reduction on the VALU pipe (no DS ops) ----
template<int CTRL>
__device__ __forceinline__ float dppf(float x) {
    return __int_as_float(__builtin_amdgcn_update_dpp(
        0, __float_as_int(x), CTRL, 0xF, 0xF, true));
}
__device__ __forceinline__ float red16_sum(float x) {
    x += dppf<0xB1>(x);
    x += dppf<0x4E>(x);
    x += dppf<0x141>(x);
    x += dppf<0x140>(x);
    return x;
}
__device__ __forceinline__ float red16_max(float x) {
    x = fmaxf(x, dppf<0xB1>(x));
    x = fmaxf(x, dppf<0x4E>(x));
    x = fmaxf(x, dppf<0x141>(x));
    x = fmaxf(x, dppf<0x140>(x));
    return x;
}

// ---------- kernel 1: fold weights (once per launch) ----------
// M2[i2, h*NI+i] = (1/sqrt(ND)) * sum_d Wq[i2, d*NH+h] * Wkv[i, d*NH+h]
// P2[h*NI+i, io] = sum_iv Wkv[i, (ND+iv)*NH+h] * Wh[h*NI+iv, io]
__global__ __launch_bounds__(256)
void precompute_MP(const float* __restrict__ Wq, const float* __restrict__ Wkv,
                   const float* __restrict__ Wh, float* __restrict__ M2, float* __restrict__ P2)
{
    int idx = blockIdx.x * 256 + threadIdx.x;        // 512 blocks
    if (idx < NI * NCOL) {
        int i  = idx & 127;
        int h  = (idx >> 7) & 3;
        int i2 = idx >> 9;
        float acc = 0.f;
        #pragma unroll 8
        for (int d = 0; d < ND; ++d)
            acc += Wq[i2 * NI + d * NH + h] * Wkv[i * KVW + d * NH + h];
        M2[i2 * NCOL + h * NI + i] = acc * 0.17677669529663687f;
    } else {
        int j  = idx - NI * NCOL;
        int io = j & 127;
        int i  = (j >> 7) & 127;
        int h  = j >> 14;
        float acc = 0.f;
        #pragma unroll 8
        for (int iv = 0; iv < NI; ++iv)
            acc += Wkv[i * KVW + (ND + iv) * NH + h] * Wh[(h * NI + iv) * NI + io];
        P2[j] = acc;   // row (h*NI+i), col io
    }
}

__device__ __forceinline__ bool load_mask(const void* p, int is_i32, int idx) {
    if (is_i32) return ((const int*)p)[idx] != 0;
    return ((const unsigned char*)p)[idx] != 0;
}

__device__ __forceinline__ void load_rows(const float4* gbase, int w, int q, int c,
                                          float4 (&A)[8], float4 (&B)[8]) {
    #pragma unroll
    for (int t = 0; t < 8; ++t) {
        int j  = 16 * t + 4 * q + w;
        int jc = (j < NNEI) ? j : 0;
        A[t] = gbase[jc * 32 + c];
        B[t] = gbase[jc * 32 + c + 16];
    }
}

// Per-atom phases: logits (DPP reduce) -> softmax -> t into s_t4a.
__device__ __forceinline__ void atom_body(
    int bl, int tid, int w, int lane, int q, int c, int is_i32,
    const float4 (&rgA)[8], const float4 (&rgB)[8],
    const float4* s_qW4a, float (*s_logit)[NNEI], float (*s_attn)[NNEI],
    float4* s_scr, float4* s_t4a,
    const void* __restrict__ mask_raw, const float* __restrict__ sw)
{
    // hoisted mask/sw loads (latency covered by phase 1 compute)
    const int j0 = lane, j1 = lane + 64;
    const int j1c = (j1 < NNEI) ? j1 : 0;
    bool m0 = load_mask(mask_raw, is_i32, bl * NNEI + j0);
    bool m1 = (j1 < NNEI) && load_mask(mask_raw, is_i32, bl * NNEI + j1c);
    float sw0 = sw[bl * NNEI + j0];
    float sw1 = (j1 < NNEI) ? sw[bl * NNEI + j1] : 0.f;

    float4 qwA[NH], qwB[NH];
    #pragma unroll
    for (int h = 0; h < NH; ++h) {
        qwA[h] = s_qW4a[h * 32 + c];
        qwB[h] = s_qW4a[h * 32 + c + 16];
    }

    // ---- phase 1: logits ----
    #pragma unroll
    for (int t = 0; t < 8; ++t) {
        float4 gA = rgA[t], gB = rgB[t];
        float s0, s1, s2, s3;
        s0 = qwA[0].x*gA.x + qwA[0].y*gA.y + qwA[0].z*gA.z + qwA[0].w*gA.w
           + qwB[0].x*gB.x + qwB[0].y*gB.y + qwB[0].z*gB.z + qwB[0].w*gB.w;
        s1 = qwA[1].x*gA.x + qwA[1].y*gA.y + qwA[1].z*gA.z + qwA[1].w*gA.w
           + qwB[1].x*gB.x + qwB[1].y*gB.y + qwB[1].z*gB.z + qwB[1].w*gB.w;
        s2 = qwA[2].x*gA.x + qwA[2].y*gA.y + qwA[2].z*gA.z + qwA[2].w*gA.w
           + qwB[2].x*gB.x + qwB[2].y*gB.y + qwB[2].z*gB.z + qwB[2].w*gB.w;
        s3 = qwA[3].x*gA.x + qwA[3].y*gA.y + qwA[3].z*gA.z + qwA[3].w*gA.w
           + qwB[3].x*gB.x + qwB[3].y*gB.y + qwB[3].z*gB.z + qwB[3].w*gB.w;
        s0 = red16_sum(s0);
        s1 = red16_sum(s1);
        s2 = red16_sum(s2);
        s3 = red16_sum(s3);
        int j = 16 * t + 4 * q + w;
        if (c == 0 && j < NNEI) {
            s_logit[0][j] = s0;
            s_logit[1][j] = s1;
            s_logit[2][j] = s2;
            s_logit[3][j] = s3;
        }
    }
    __syncthreads();

    // ---- masked softmax + *sw : wave w handles head h=w ----
    {
        float v0 = m0 ? s_logit[w][j0] : -INFINITY;
        float v1 = m1 ? s_logit[w][j1c] : -INFINITY;
        float mx = fmaxf(v0, v1);
        mx = red16_max(mx);
        mx = fmaxf(mx, __shfl_xor(mx, 16));
        mx = fmaxf(mx, __shfl_xor(mx, 32));
        float e0 = 0.f, e1 = 0.f;
        if (mx != -INFINITY) {
            e0 = m0 ? __expf(v0 - mx) : 0.f;
            e1 = m1 ? __expf(v1 - mx) : 0.f;
        }
        float s = e0 + e1;
        s = red16_sum(s);
        s += __shfl_xor(s, 16);
        s += __shfl_xor(s, 32);
        float inv = (s > 0.f) ? (1.f / s) : 0.f;
        s_attn[w][j0] = e0 * inv * sw0;
        if (j1 < NNEI) s_attn[w][j1] = e1 * inv * sw1;
    }
    __syncthreads();

    // ---- phase 2: per-(wave,q) partial t rows -> s_scr [16][4][33] ----
    {
        float4 aA[NH] = {}, aB[NH] = {};
        #pragma unroll
        for (int t = 0; t < 8; ++t) {
            int j = 16 * t + 4 * q + w;
            bool val = (j < NNEI);
            float4 gA = rgA[t], gB = rgB[t];
            #pragma unroll
            for (int h = 0; h < NH; ++h) {
                float a = val ? s_attn[h][j] : 0.f;
                aA[h].x += a * gA.x; aA[h].y += a * gA.y;
                aA[h].z += a * gA.z; aA[h].w += a * gA.w;
                aB[h].x += a * gB.x; aB[h].y += a * gB.y;
                aB[h].z += a * gB.z; aB[h].w += a * gB.w;
            }
        }
        int grp = w * 4 + q;
        #pragma unroll
        for (int h = 0; h < NH; ++h) {
            s_scr[grp * 132 + h * 33 + c]      = aA[h];
            s_scr[grp * 132 + h * 33 + c + 16] = aB[h];
        }
    }
    __syncthreads();

    // ---- fold 16 partials -> s_t4a ----
    if (tid < 128) {
        int h = tid >> 5, cc = tid & 31;
        float4 r = {0.f, 0.f, 0.f, 0.f};
        #pragma unroll
        for (int g = 0; g < 16; ++g) {
            float4 v = s_scr[g * 132 + h * 33 + cc];
            r.x += v.x; r.y += v.y; r.z += v.z; r.w += v.w;
        }
        s_t4a[h * 32 + cc] = r;
    }
    __syncthreads();
}

// ---------- fused kernel: qW GEMM + attention + out GEMM, ATOMS atoms/block ----------
__global__ __launch_bounds__(256, 2)
void fused_atten(const float* __restrict__ g1, const float* __restrict__ gg1,
                 const void* __restrict__ mask_raw, const float* __restrict__ sw,
                 const float* __restrict__ M2, const float* __restrict__ P2,
                 const float* __restrict__ bh, float* __restrict__ out)
{
    __shared__ float  s_g1[ATOMS][NI];        // 2 KB
    __shared__ float4 s_qW4[ATOMS][NI];       // 8 KB  qW[a] as 128 float4 (h*32+slot)
    __shared__ float  s_logit[NH][NNEI];      // 1.9 KB
    __shared__ float  s_attn[NH][NNEI];       // 1.9 KB
    __shared__ float4 s_t4[ATOMS][NI];        // 8 KB  t[a] as 128 float4
    __shared__ float4 s_scr[2112];            // 33.8 KB union scratch
    __shared__ int    s_is_i32;

    const int tid  = threadIdx.x;
    const int bl0  = blockIdx.x * ATOMS;
    const int w    = tid >> 6;
    const int lane = tid & 63;
    const int q    = lane >> 4;
    const int c    = lane & 15;

    if (tid < 64) {
        unsigned v = ((const unsigned*)mask_raw)[tid];
        unsigned long long b = __ballot(v <= 1u);
        if (tid == 0) s_is_i32 = (b == 0xFFFFFFFFFFFFFFFFull) ? 1 : 0;
    }
    if (tid < ATOMS * NI / 4)
        ((float4*)s_g1)[tid] = ((const float4*)(g1 + (size_t)bl0 * NI))[tid];

    // issue gg1 register loads for atoms 0 and 1 (latency hidden by M2 pass)
    const float4* gb0 = (const float4*)(gg1 + (size_t)(bl0 + 0) * NNEI * NI);
    const float4* gb1 = (const float4*)(gg1 + (size_t)(bl0 + 1) * NNEI * NI);
    const float4* gb2 = (const float4*)(gg1 + (size_t)(bl0 + 2) * NNEI * NI);
    const float4* gb3 = (const float4*)(gg1 + (size_t)(bl0 + 3) * NNEI * NI);
    float4 rA0[8], rB0[8], rA1[8], rB1[8];
    load_rows(gb0, w, q, c, rA0, rB0);
    load_rows(gb1, w, q, c, rA1, rB1);

    __syncthreads();
    const int is_i32 = s_is_i32;

    // ---- M2 pass: qW[a][col] = sum_i2 g1[a][i2] * M2[i2][col] ----
    {
        const int col4 = tid & 127, halfk = tid >> 7;
        float4 acc[ATOMS] = {};
        const float4* M2_4 = (const float4*)M2;      // [128][128] float4
        #pragma unroll 8
        for (int it = 0; it < 64; ++it) {
            int i2 = it * 2 + halfk;
            float4 m = M2_4[i2 * 128 + col4];
            #pragma unroll
            for (int a = 0; a < ATOMS; ++a) {
                float gv = s_g1[a][i2];
                acc[a].x += gv * m.x; acc[a].y += gv * m.y;
                acc[a].z += gv * m.z; acc[a].w += gv * m.w;
            }
        }
        #pragma unroll
        for (int a = 0; a < ATOMS; ++a)
            s_scr[(halfk * ATOMS + a) * 129 + col4] = acc[a];
    }
    __syncthreads();
    {
        #pragma unroll
        for (int e = 0; e < 2; ++e) {
            int idx = tid + e * 256;
            int a = idx >> 7, c4 = idx & 127;
            float4 x = s_scr[a * 129 + c4];
            float4 y = s_scr[(4 + a) * 129 + c4];
            float4 r; r.x = x.x + y.x; r.y = x.y + y.y; r.z = x.z + y.z; r.w = x.w + y.w;
            s_qW4[a][c4] = r;
        }
    }
    __syncthreads();

    // ---- atoms, two register sets, next-atom loads issued early ----
    atom_body(bl0 + 0, tid, w, lane, q, c, is_i32, rA0, rB0,
              &s_qW4[0][0], s_logit, s_attn, s_scr, &s_t4[0][0], mask_raw, sw);
    load_rows(gb2, w, q, c, rA0, rB0);
    atom_body(bl0 + 1, tid, w, lane, q, c, is_i32, rA1, rB1,
              &s_qW4[1][0], s_logit, s_attn, s_scr, &s_t4[1][0], mask_raw, sw);
    load_rows(gb3, w, q, c, rA1, rB1);
    atom_body(bl0 + 2, tid, w, lane, q, c, is_i32, rA0, rB0,
              &s_qW4[2][0], s_logit, s_attn, s_scr, &s_t4[2][0], mask_raw, sw);
    atom_body(bl0 + 3, tid, w, lane, q, c, is_i32, rA1, rB1,
              &s_qW4[3][0], s_logit, s_attn, s_scr, &s_t4[3][0], mask_raw, sw);

    // ---- P2 pass: out[a][io] = bh[io] + sum_kk t[a][kk] * P2[kk][io] ----
    {
        const int io4 = tid & 31, g = tid >> 5;       // g in 0..7
        float4 oacc[ATOMS] = {};
        const float4* P2_4 = (const float4*)P2;       // [512][32] float4
        const float*  s_tf = (const float*)s_t4;
        #pragma unroll 8
        for (int it = 0; it < 64; ++it) {
            int kk = it * 8 + g;
            float4 p = P2_4[kk * 32 + io4];
            #pragma unroll
            for (int a = 0; a < ATOMS; ++a) {
                float tv = s_tf[a * NCOL + kk];       // wave-broadcast LDS read
                oacc[a].x += tv * p.x; oacc[a].y += tv * p.y;
                oacc[a].z += tv * p.z; oacc[a].w += tv * p.w;
            }
        }
        #pragma unroll
        for (int a = 0; a < ATOMS; ++a)
            s_scr[(g * ATOMS + a) * 33 + io4] = oacc[a];
    }
    __syncthreads();
    if (tid < 128) {
        int a = tid >> 5, io4 = tid & 31;
        float4 r = {0.f, 0.f, 0.f, 0.f};
        #pragma unroll
        for (int g = 0; g < 8; ++g) {
            float4 v = s_scr[(g * ATOMS + a) * 33 + io4];
            r.x += v.x; r.y += v.y; r.z += v.z; r.w += v.w;
        }
        float4 b = ((const float4*)bh)[io4];
        r.x += b.x; r.y += b.y; r.z += b.z; r.w += b.w;
        ((float4*)out)[(size_t)(bl0 + a) * 32 + io4] = r;
    }
}

// ---------- fallback: single fused kernel (round-2 structure, M2/P2 layouts) ----------
__global__ __launch_bounds__(256, 2)
void fused_fallback(const float* __restrict__ g1, const float* __restrict__ gg1,
                    const void* __restrict__ mask_raw, const float* __restrict__ sw,
                    const float* __restrict__ M2, const float* __restrict__ P2,
                    const float* __restrict__ bh, float* __restrict__ out)
{
    __shared__ float s_gg[NNEI * 129];
    __shared__ float s_qW[NH][NI];
    __shared__ float s_attn[NH][NNEI];
    __shared__ float s_t[NH][NI];
    __shared__ float s_part[2][NI];
    __shared__ int   s_is_i32;

    const int tid = threadIdx.x;
    const int bl  = blockIdx.x;

    if (tid < 64) {
        unsigned v = ((const unsigned*)mask_raw)[tid];
        unsigned long long b = __ballot(v <= 1u);
        if (tid == 0) s_is_i32 = (b == 0xFFFFFFFFFFFFFFFFull) ? 1 : 0;
    }
    {
        const float4* gsrc = (const float4*)(gg1 + (size_t)bl * NNEI * NI);
        #pragma unroll
        for (int p = 0; p < 15; ++p) {
            int u = tid + p * 256;
            int r = u >> 5, c4 = u & 31;
            float4 v = gsrc[u];
            float* dst = &s_gg[r * 129 + c4 * 4];
            dst[0] = v.x; dst[1] = v.y; dst[2] = v.z; dst[3] = v.w;
        }
    }
    {
        const float* g1r = g1 + bl * NI;
        #pragma unroll
        for (int p = 0; p < 2; ++p) {
            int o = tid + p * 256;
            int i = o & (NI - 1);
            int h = o >> 7;
            const float* Mp = M2 + h * NI + i;
            float acc = 0.f;
            #pragma unroll 8
            for (int i2 = 0; i2 < NI; ++i2) acc += g1r[i2] * Mp[i2 * NCOL];
            s_qW[h][i] = acc;
        }
    }
    __syncthreads();
    {
        const int lane = tid & 63, h = tid >> 6;
        const int j0 = lane, j1 = lane + 64;
        const int j1c = (j1 < NNEI) ? j1 : 0;
        const float* row0 = &s_gg[j0 * 129];
        const float* row1 = &s_gg[j1c * 129];
        float dot0 = 0.f, dot1 = 0.f;
        #pragma unroll 8
        for (int i = 0; i < NI; ++i) {
            float w = s_qW[h][i];
            dot0 += row0[i] * w;
            dot1 += row1[i] * w;
        }
        bool m0 = load_mask(mask_raw, s_is_i32, bl * NNEI + j0);
        bool m1 = (j1 < NNEI) && load_mask(mask_raw, s_is_i32, bl * NNEI + j1c);
        float v0 = m0 ? dot0 : -INFINITY;
        float v1 = m1 ? dot1 : -INFINITY;
        float mx = fmaxf(v0, v1);
        #pragma unroll
        for (int off = 32; off; off >>= 1) mx = fmaxf(mx, __shfl_xor(mx, off));
        float e0 = 0.f, e1 = 0.f;
        if (mx != -INFINITY) {
            e0 = m0 ? __expf(v0 - mx) : 0.f;
            e1 = m1 ? __expf(v1 - mx) : 0.f;
        }
        float s = e0 + e1;
        #pragma unroll
        for (int off = 32; off; off >>= 1) s += __shfl_xor(s, off);
        float inv = (s > 0.f) ? (1.f / s) : 0.f;
        s_attn[h][j0] = e0 * inv * sw[bl * NNEI + j0];
        if (j1 < NNEI) s_attn[h][j1] = e1 * inv * sw[bl * NNEI + j1];
    }
    __syncthreads();
    #pragma unroll
    for (int p = 0; p < 2; ++p) {
        int o = tid + p * 256;
        int i = o & (NI - 1);
        int h = o >> 7;
        float acc = 0.f;
        #pragma unroll 8
        for (int j = 0; j < NNEI; ++j) acc += s_attn[h][j] * s_gg[j * 129 + i];
        s_t[h][i] = acc;
    }
    __syncthreads();
    {
        int io = tid & (NI - 1);
        int half = tid >> 7;
        float acc = 0.f;
        #pragma unroll 2
        for (int h = half * 2; h < half * 2 + 2; ++h) {
            const float* Pp = P2 + h * NI * NI + io;
            #pragma unroll 8
            for (int i = 0; i < NI; ++i) acc += s_t[h][i] * Pp[i * NI];
        }
        s_part[half][io] = acc;
    }
    __syncthreads();
    if (tid < NI)
        out[bl * NI + tid] = s_part[0][tid] + s_part[1][tid] + bh[tid];
}

extern "C" void kernel_launch(void* const* d_in, const int* in_sizes, int n_in,
                              void* d_out, int out_size, void* d_ws, size_t ws_size,
                              hipStream_t stream) {
    const float* g1   = (const float*)d_in[0];
    const float* gg1  = (const float*)d_in[1];
    const void*  mask = d_in[2];
    const float* sw   = (const float*)d_in[3];
    const float* Wq   = (const float*)d_in[4];
    const float* Wkv  = (const float*)d_in[5];
    const float* Wh   = (const float*)d_in[6];
    const float* bh   = (const float*)d_in[7];
    float* out = (float*)d_out;

    const int nbl = in_sizes[0] / NI;                 // nb*nloc = 2048
    const size_t nM = (size_t)NI * NCOL;              // 65536
    const size_t nP = (size_t)NCOL * NI;              // 65536

    float* M2 = (float*)d_ws;
    float* P2 = M2 + nM;

    precompute_MP<<<512, 256, 0, stream>>>(Wq, Wkv, Wh, M2, P2);

    if ((nbl % ATOMS) == 0) {
        fused_atten<<<nbl / ATOMS, 256, 0, stream>>>(g1, gg1, mask, sw, M2, P2, bh, out);
    } else {
        fused_fallback<<<nbl, 256, 0, stream>>>(g1, gg1, mask, sw, M2, P2, bh, out);
    }
}